// Round 17
// baseline (224.767 us; speedup 1.0000x reference)
//
#include <hip/hip_runtime.h>

typedef float f32x4 __attribute__((ext_vector_type(4)));
typedef int   i32x4 __attribute__((ext_vector_type(4)));

namespace {
constexpr int   B_    = 2;
constexpr int   N_    = 250000;
constexpr int   C_    = 64;
constexpr int   NX_   = 1024;
constexpr int   NY_   = 1024;
constexpr int   CELLS = NX_ * NY_;          // 1<<20
constexpr int   TOT   = B_ * CELLS;         // 2,097,152
constexpr float VS0   = 0.1f, VS1 = 0.1f;
constexpr float PC0   = -51.2f, PC1 = -51.2f;
constexpr float EPS_  = 1e-5f;

constexpr int   PBLK  = (N_ + 255) / 256;   // 977 pass1 blocks per batch
constexpr int   GRID  = 2048;               // fat kernel blocks (8192 waves)
constexpr int   NSTRIPE = (B_ * C_ * CELLS) / 2048;  // 65536 stripes of 2048 cells (8 KB)

// ---- d_ws layout (4B units) ----
constexpr int WS_W1T  = 0;                    // [64][10] folded
constexpr int WS_B1   = 640;                  // [64]
constexpr int WS_W2T  = 704;                  // [64][64] c-major
constexpr int WS_B2   = 4800;                 // [64]
constexpr int WS_PZ   = 4864;                 // [B][1024] z partials
constexpr int WS_PM   = WS_PZ + 2048;         // [B][1024] count partials
constexpr int WS_CNT  = WS_PM + 2048;         // occupied-cell counter
constexpr int WS_HEAD = 16384;                // [TOT] per-cell list head (-1 empty)
constexpr int WS_NEXT = WS_HEAD + TOT;        // [B*N] next-point link
constexpr int WS_LIST = WS_NEXT + B_ * N_;    // [<=B*N] occupied cell list
constexpr int WS_BMP  = WS_LIST + B_ * N_;    // [TOT/32] occupancy bitmap
constexpr int WS_END  = WS_BMP + TOT / 32;
constexpr size_t NEED_BYTES = (size_t)WS_END * 4;
}

// Kernel 1: init head/-1, bitmap/partials/counters/0; block 0 folds BN weights.
__global__ __launch_bounds__(256) void init_prep(const float* __restrict__ W1, const float* __restrict__ g1,
                                                 const float* __restrict__ b1, const float* __restrict__ m1,
                                                 const float* __restrict__ v1, const float* __restrict__ W2,
                                                 const float* __restrict__ g2, const float* __restrict__ b2,
                                                 const float* __restrict__ m2, const float* __restrict__ v2,
                                                 float* __restrict__ wsf, int* __restrict__ wsi) {
    const int tid    = blockIdx.x * 256 + threadIdx.x;
    const int stride = gridDim.x * 256;
    i32x4* head4 = (i32x4*)(wsi + WS_HEAD);
    i32x4* bmp4  = (i32x4*)(wsi + WS_BMP);
    const i32x4 mone = {-1, -1, -1, -1};
    const i32x4 zero = {0, 0, 0, 0};
    for (int i = tid; i < TOT / 4; i += stride) __builtin_nontemporal_store(mone, head4 + i);
    for (int i = tid; i < TOT / 32 / 4; i += stride) __builtin_nontemporal_store(zero, bmp4 + i);
    if (tid < 1024) ((i32x4*)(wsi + WS_PZ))[tid] = zero;   // PZ+PM (4096 ints)
    if (tid == 0) wsi[WS_CNT] = 0;
    if (blockIdx.x == 0 && threadIdx.x < C_) {
        const int c = threadIdx.x;
        float s1 = g1[c] / sqrtf(v1[c] + EPS_);
        for (int f = 0; f < 10; ++f) wsf[WS_W1T + c * 10 + f] = W1[f * C_ + c] * s1;
        wsf[WS_B1 + c] = b1[c] - m1[c] * s1;
        float s2 = g2[c] / sqrtf(v2[c] + EPS_);
        for (int k = 0; k < C_; ++k) wsf[WS_W2T + c * C_ + k] = W2[k * C_ + c] * s2;
        wsf[WS_B2 + c] = b2[c] - m2[c] * s2;
    }
}

__device__ __forceinline__ int cell_of(float x, float y) {
    int px = (int)floorf((x - PC0) / VS0);
    int py = (int)floorf((y - PC1) / VS1);
    px = px < 0 ? 0 : (px > NX_ - 1 ? NX_ - 1 : px);
    py = py < 0 ? 0 : (py > NY_ - 1 ? NY_ - 1 : py);
    return py * NX_ + px;
}

// Kernel 2: one coalesced sweep — z-mean partials + linked-list insert +
// occupied-list append + bitmap set (first insert per cell).
__global__ __launch_bounds__(256) void pass1(const float* __restrict__ pts,
                                             const int* __restrict__ mask,
                                             float* __restrict__ wsf, int* __restrict__ wsi) {
    const int b = blockIdx.y, t = threadIdx.x;
    const int n = blockIdx.x * 256 + t;
    float sz = 0.f, sm = 0.f;
    if (n < N_ && mask[b * N_ + n]) {
        const size_t pb = ((size_t)b * N_ + n) * 5;
        const float x = pts[pb], y = pts[pb + 1], z = pts[pb + 2];
        const int idx = b * CELLS + cell_of(x, y);
        const int old = atomicExch(&wsi[WS_HEAD + idx], n);
        wsi[WS_NEXT + b * N_ + n] = old;
        if (old == -1) {
            const int li = atomicAdd(&wsi[WS_CNT], 1);
            wsi[WS_LIST + li] = idx;
            atomicOr(&wsi[WS_BMP + (idx >> 5)], 1 << (idx & 31));
        }
        sz = z; sm = 1.f;
    }
    __shared__ float lz[256], lm[256];
    lz[t] = sz; lm[t] = sm;
    __syncthreads();
    for (int s = 128; s > 0; s >>= 1) {
        if (t < s) { lz[t] += lz[t + s]; lm[t] += lm[t + s]; }
        __syncthreads();
    }
    if (t == 0) { wsf[WS_PZ + b * 1024 + blockIdx.x] = lz[0]; wsf[WS_PM + b * 1024 + blockIdx.x] = lm[0]; }
}

// Kernel 3: round-16 body with ONE structural change: the compute loop and
// zero loop are MERGED into a fine-grained interleave — each iteration does
// {1 cell compute, 2 stripe zeros}. NT stores are fire-and-forget, so their
// HBM drain proceeds UNDER the next cell's ~4000cy of chain-walk compute:
// per-wave overlap of the VALU-bound and HBM-bound phases without the
// round-13 stagger failure (no cross-wave phase split, no idle tail).
// Store sets disjoint via bitmap; fmax exact -> bit-identical output.
__global__ __launch_bounds__(256) void fat(const float* __restrict__ pts,
                                           const float* __restrict__ wsf,
                                           const int* __restrict__ wsi,
                                           float* __restrict__ out) {
    __shared__ float red[16];
    const int t    = threadIdx.x;
    const int wid  = t >> 6;
    const int lane = t & 63;
    const int c    = lane;

    // ---- zmean finish: reduce 1024 partials per batch, redundantly per block ----
    float sz0 = 0.f, sm0 = 0.f, sz1 = 0.f, sm1 = 0.f;
#pragma unroll
    for (int k = 0; k < 4; ++k) {
        const int i = t + k * 256;
        sz0 += wsf[WS_PZ + i];        sm0 += wsf[WS_PM + i];
        sz1 += wsf[WS_PZ + 1024 + i]; sm1 += wsf[WS_PM + 1024 + i];
    }
#pragma unroll
    for (int m = 32; m >= 1; m >>= 1) {
        sz0 += __shfl_xor(sz0, m, 64); sm0 += __shfl_xor(sm0, m, 64);
        sz1 += __shfl_xor(sz1, m, 64); sm1 += __shfl_xor(sm1, m, 64);
    }
    if (lane == 0) {
        red[wid * 4 + 0] = sz0; red[wid * 4 + 1] = sm0;
        red[wid * 4 + 2] = sz1; red[wid * 4 + 3] = sm1;
    }
    __syncthreads();
    const float zm0 = (red[0] + red[4] + red[8] + red[12]) /
                      fmaxf(red[1] + red[5] + red[9] + red[13], 1.f);
    const float zm1 = (red[2] + red[6] + red[10] + red[14]) /
                      fmaxf(red[3] + red[7] + red[11] + red[15], 1.f);

    // ---- per-lane folded weights ----
    float w1c[10];
#pragma unroll
    for (int f = 0; f < 10; ++f) w1c[f] = wsf[WS_W1T + c * 10 + f];
    const float b1c = wsf[WS_B1 + c];
    float w2c[C_];
#pragma unroll
    for (int k = 0; k < C_; ++k) w2c[k] = wsf[WS_W2T + c * C_ + k];
    const float b2c = wsf[WS_B2 + c];

    const int W  = blockIdx.x * 4 + wid;
    const int NW = GRID * 4;
    const int cnt = wsi[WS_CNT];

    f32x4* out4 = (f32x4*)out;
    const f32x4 z4 = {0.f, 0.f, 0.f, 0.f};

    int e = W;   // next cell to compute
    int s = W;   // next stripe to zero
    while (e < cnt || s < NSTRIPE) {
        // ---- one cell of compute (2-deep pipelined chain walk) ----
        if (e < cnt) {
            const int idx  = wsi[WS_LIST + e];
            const int b    = idx >> 20;
            const int cell = idx & (CELLS - 1);
            const float pxf = (float)(cell & (NX_ - 1));
            const float pyf = (float)(cell >> 10);
            const float zmean = b ? zm1 : zm0;
            const int nb = b * N_;
            float hmax = 0.f;

            int n0 = wsi[WS_HEAD + idx];
            int n1 = -1;
            float x0 = 0.f, y0 = 0.f, z0 = 0.f, i0 = 0.f, r0 = 0.f;
            float x1 = 0.f, y1 = 0.f, z1 = 0.f, i1 = 0.f, r1 = 0.f;
            if (n0 != -1) {
                const size_t pb = ((size_t)nb + n0) * 5;
                x0 = pts[pb]; y0 = pts[pb + 1]; z0 = pts[pb + 2];
                i0 = pts[pb + 3]; r0 = pts[pb + 4];
                n1 = wsi[WS_NEXT + nb + n0];
            }
            while (n0 != -1) {
                int n2 = -1;
                if (n1 != -1) {                      // issue next point's loads NOW
                    n2 = wsi[WS_NEXT + nb + n1];
                    const size_t pb = ((size_t)nb + n1) * 5;
                    x1 = pts[pb]; y1 = pts[pb + 1]; z1 = pts[pb + 2];
                    i1 = pts[pb + 3]; r1 = pts[pb + 4];
                }
                float a = b1c;
                a = fmaf(x0, w1c[0], a);
                a = fmaf(y0, w1c[1], a);
                a = fmaf(z0, w1c[2], a);
                a = fmaf(i0, w1c[3], a);
                a = fmaf(r0, w1c[4], a);
                a = fmaf(x0 - (pxf * VS0 + PC0 + VS0 * 0.5f), w1c[5], a);
                a = fmaf(y0 - (pyf * VS1 + PC1 + VS1 * 0.5f), w1c[6], a);
                a = fmaf(z0 - zmean,                          w1c[7], a);
                a = fmaf(x0 - (pxf * VS0 + PC0),              w1c[8], a);
                a = fmaf(y0 - (pyf * VS1 + PC1),              w1c[9], a);
                const int h1i = __float_as_int(fmaxf(a, 0.f));   // lane k holds h1[k]
                float ac0 = 0.f, ac1 = 0.f, ac2 = 0.f, ac3 = 0.f;
#pragma unroll
                for (int k = 0; k < 16; ++k) {   // same k-order + 4-way split as rounds 2-16
                    ac0 = fmaf(__int_as_float(__builtin_amdgcn_readlane(h1i, 4 * k + 0)), w2c[4 * k + 0], ac0);
                    ac1 = fmaf(__int_as_float(__builtin_amdgcn_readlane(h1i, 4 * k + 1)), w2c[4 * k + 1], ac1);
                    ac2 = fmaf(__int_as_float(__builtin_amdgcn_readlane(h1i, 4 * k + 2)), w2c[4 * k + 2], ac2);
                    ac3 = fmaf(__int_as_float(__builtin_amdgcn_readlane(h1i, 4 * k + 3)), w2c[4 * k + 3], ac3);
                }
                hmax = fmaxf(hmax, b2c + ((ac0 + ac1) + (ac2 + ac3)));
                n0 = n1; n1 = n2;
                x0 = x1; y0 = y1; z0 = z1; i0 = i1; r0 = r1;
            }
            out[(((size_t)b * C_ + c) << 20) + cell] = hmax;
            e += NW;
        }

        // ---- two stripes of zeroing (stores drain under the next cell) ----
#pragma unroll
        for (int r = 0; r < 2; ++r) {
            if (s >= NSTRIPE) break;
            const int p  = s >> 9;          // plane = b*64 + ch
            const int q  = s & 511;         // stripe within plane (2048 cells)
            const int bb = p >> 6;
            const int Wd = wsi[WS_BMP + bb * (CELLS / 32) + q * 64 + lane];
            const int ib = (p << 18) + (q << 9);   // f32x4 base index of stripe
            if (__ballot(Wd != 0) == 0ULL) {
#pragma unroll
                for (int k = 0; k < 8; ++k)
                    __builtin_nontemporal_store(z4, out4 + (ib + k * 64 + lane));
            } else {
#pragma unroll
                for (int k = 0; k < 8; ++k) {
                    const unsigned w   = (unsigned)__shfl(Wd, k * 8 + (lane >> 3), 64);
                    const unsigned nib = (w >> ((lane & 7) * 4)) & 0xFu;
                    const int i = ib + k * 64 + lane;
                    if (nib == 0u) {
                        __builtin_nontemporal_store(z4, out4 + i);
                    } else {
#pragma unroll
                        for (int jj = 0; jj < 4; ++jj)
                            if (!((nib >> jj) & 1u)) out[(size_t)i * 4 + jj] = 0.f;
                    }
                }
            }
            s += NW;
        }
    }
}

// ---------------- fallback path (round-2, atomic scatter) ----------------
__global__ void prep_weights_fb(const float* __restrict__ W1, const float* __restrict__ g1,
                                const float* __restrict__ b1, const float* __restrict__ m1,
                                const float* __restrict__ v1, const float* __restrict__ W2,
                                const float* __restrict__ g2, const float* __restrict__ b2,
                                const float* __restrict__ m2, const float* __restrict__ v2,
                                float* __restrict__ ws) {
    int c = threadIdx.x;
    if (c >= C_) return;
    float s1 = g1[c] / sqrtf(v1[c] + EPS_);
    for (int f = 0; f < 10; ++f) ws[WS_W1T + c * 10 + f] = W1[f * C_ + c] * s1;
    ws[WS_B1 + c] = b1[c] - m1[c] * s1;
    float s2 = g2[c] / sqrtf(v2[c] + EPS_);
    for (int k = 0; k < C_; ++k) ws[WS_W2T + c * C_ + k] = W2[k * C_ + c] * s2;
    ws[WS_B2 + c] = b2[c] - m2[c] * s2;
}

__global__ void zmean_fb1(const float* __restrict__ pts, const int* __restrict__ mask,
                          float* __restrict__ ws) {
    const int b = blockIdx.y, t = threadIdx.x;
    const int n = blockIdx.x * 256 + t;
    float sz = 0.f, sm = 0.f;
    if (n < N_ && mask[b * N_ + n]) {
        sz = pts[((size_t)b * N_ + n) * 5 + 2];
        sm = 1.f;
    }
    __shared__ float lz[256], lm[256];
    lz[t] = sz; lm[t] = sm;
    __syncthreads();
    for (int s = 128; s > 0; s >>= 1) {
        if (t < s) { lz[t] += lz[t + s]; lm[t] += lm[t + s]; }
        __syncthreads();
    }
    if (t == 0) { ws[WS_PZ + b * 1024 + blockIdx.x] = lz[0]; ws[WS_PM + b * 1024 + blockIdx.x] = lm[0]; }
}

__global__ void zmean_fb2(float* __restrict__ ws) {
    const int b = blockIdx.x, t = threadIdx.x;
    __shared__ float lz[256], lm[256];
    float sz = 0.f, sm = 0.f;
    for (int k = t; k < 1024; k += 256) {
        sz += (k < PBLK) ? ws[WS_PZ + b * 1024 + k] : 0.f;
        sm += (k < PBLK) ? ws[WS_PM + b * 1024 + k] : 0.f;
    }
    lz[t] = sz; lm[t] = sm;
    __syncthreads();
    for (int s = 128; s > 0; s >>= 1) {
        if (t < s) { lz[t] += lz[t + s]; lm[t] += lm[t + s]; }
        __syncthreads();
    }
    if (t == 0) ws[WS_CNT + 2 + b] = lz[0] / fmaxf(lm[0], 1.f);  // stash zmean
}

__global__ __launch_bounds__(256) void pfn_scatter_fb(const float* __restrict__ pts,
                                                      const int* __restrict__ mask,
                                                      const float* __restrict__ ws,
                                                      float* __restrict__ out) {
    const int b = blockIdx.y;
    const int n = blockIdx.x * 256 + threadIdx.x;
    if (n >= N_) return;
    if (!mask[b * N_ + n]) return;
    const float zmean = ws[WS_CNT + 2 + b];
    const size_t pbase = ((size_t)b * N_ + n) * 5;
    const float x = pts[pbase], y = pts[pbase + 1], z = pts[pbase + 2];
    const float it = pts[pbase + 3], rg = pts[pbase + 4];
    const int cell = cell_of(x, y);
    const float pxf = (float)(cell & (NX_ - 1)), pyf = (float)(cell >> 10);
    float aug[10];
    aug[0] = x; aug[1] = y; aug[2] = z; aug[3] = it; aug[4] = rg;
    aug[5] = x - (pxf * VS0 + PC0 + VS0 * 0.5f);
    aug[6] = y - (pyf * VS1 + PC1 + VS1 * 0.5f);
    aug[7] = z - zmean;
    aug[8] = x - (pxf * VS0 + PC0);
    aug[9] = y - (pyf * VS1 + PC1);
    float h1[C_];
#pragma unroll
    for (int c = 0; c < C_; ++c) {
        float acc = ws[WS_B1 + c];
#pragma unroll
        for (int f = 0; f < 10; ++f) acc = fmaf(aug[f], ws[WS_W1T + c * 10 + f], acc);
        h1[c] = fmaxf(acc, 0.f);
    }
    unsigned int* ob = (unsigned int*)out + (size_t)b * C_ * CELLS + cell;
#pragma unroll 4
    for (int c = 0; c < C_; ++c) {
        float acc = ws[WS_B2 + c];
#pragma unroll
        for (int k = 0; k < C_; ++k) acc = fmaf(h1[k], ws[WS_W2T + c * C_ + k], acc);
        if (acc > 0.f) atomicMax(ob + (size_t)c * CELLS, __float_as_uint(acc));
    }
}

extern "C" void kernel_launch(void* const* d_in, const int* in_sizes, int n_in,
                              void* d_out, int out_size, void* d_ws, size_t ws_size,
                              hipStream_t stream) {
    const float* pts  = (const float*)d_in[0];
    const int*   mask = (const int*)d_in[1];
    const float* W1 = (const float*)d_in[2];
    const float* g1 = (const float*)d_in[3];
    const float* b1 = (const float*)d_in[4];
    const float* m1 = (const float*)d_in[5];
    const float* v1 = (const float*)d_in[6];
    const float* W2 = (const float*)d_in[7];
    const float* g2 = (const float*)d_in[8];
    const float* b2 = (const float*)d_in[9];
    const float* m2 = (const float*)d_in[10];
    const float* v2 = (const float*)d_in[11];
    float* wsf = (float*)d_ws;
    int*   wsi = (int*)d_ws;
    float* out = (float*)d_out;

    if (ws_size >= NEED_BYTES) {
        init_prep<<<512, 256, 0, stream>>>(W1, g1, b1, m1, v1, W2, g2, b2, m2, v2, wsf, wsi);
        pass1<<<dim3(PBLK, B_), 256, 0, stream>>>(pts, mask, wsf, wsi);
        fat<<<GRID, 256, 0, stream>>>(pts, wsf, wsi, out);
    } else {
        hipMemsetAsync(d_out, 0, (size_t)out_size * sizeof(float), stream);
        hipMemsetAsync((char*)d_ws + (size_t)WS_PZ * 4, 0, 4096 * 4, stream);
        prep_weights_fb<<<1, 256, 0, stream>>>(W1, g1, b1, m1, v1, W2, g2, b2, m2, v2, wsf);
        zmean_fb1<<<dim3(PBLK, B_), 256, 0, stream>>>(pts, mask, wsf);
        zmean_fb2<<<B_, 256, 0, stream>>>(wsf);
        pfn_scatter_fb<<<dim3((N_ + 255) / 256, B_), 256, 0, stream>>>(pts, mask, wsf, out);
    }
}

// Round 18
// 208.492 us; speedup vs baseline: 1.0781x; 1.0781x over previous
//
#include <hip/hip_runtime.h>

typedef float f32x4 __attribute__((ext_vector_type(4)));
typedef int   i32x4 __attribute__((ext_vector_type(4)));

namespace {
constexpr int   B_    = 2;
constexpr int   N_    = 250000;
constexpr int   C_    = 64;
constexpr int   NX_   = 1024;
constexpr int   NY_   = 1024;
constexpr int   CELLS = NX_ * NY_;          // 1<<20
constexpr int   TOT   = B_ * CELLS;         // 2,097,152
constexpr float VS0   = 0.1f, VS1 = 0.1f;
constexpr float PC0   = -51.2f, PC1 = -51.2f;
constexpr float EPS_  = 1e-5f;

constexpr int   PBLK  = (N_ + 255) / 256;   // 977 pass1 blocks per batch
constexpr int   GRID  = 2048;               // fat kernel blocks (8192 waves)
constexpr int   NSTRIPE = (B_ * C_ * CELLS) / 2048;  // 65536 stripes of 2048 cells (8 KB)

// ---- d_ws layout (4B units) ----
constexpr int WS_W1T  = 0;                    // [64][10] folded
constexpr int WS_B1   = 640;                  // [64]
constexpr int WS_W2T  = 704;                  // [64][64] c-major
constexpr int WS_B2   = 4800;                 // [64]
constexpr int WS_PZ   = 4864;                 // [B][1024] z partials
constexpr int WS_PM   = WS_PZ + 2048;         // [B][1024] count partials
constexpr int WS_CNT  = WS_PM + 2048;         // occupied-cell counter
constexpr int WS_HEAD = 16384;                // [TOT] per-cell list head (-1 empty)
constexpr int WS_NEXT = WS_HEAD + TOT;        // [B*N] next-point link
constexpr int WS_LIST = WS_NEXT + B_ * N_;    // [<=B*N] occupied cell list
constexpr int WS_BMP  = WS_LIST + B_ * N_;    // [TOT/32] occupancy bitmap
constexpr int WS_END  = WS_BMP + TOT / 32;
constexpr size_t NEED_BYTES = (size_t)WS_END * 4;
}

// Kernel 1: init head/-1, bitmap/partials/counters/0; block 0 folds BN weights.
__global__ __launch_bounds__(256) void init_prep(const float* __restrict__ W1, const float* __restrict__ g1,
                                                 const float* __restrict__ b1, const float* __restrict__ m1,
                                                 const float* __restrict__ v1, const float* __restrict__ W2,
                                                 const float* __restrict__ g2, const float* __restrict__ b2,
                                                 const float* __restrict__ m2, const float* __restrict__ v2,
                                                 float* __restrict__ wsf, int* __restrict__ wsi) {
    const int tid    = blockIdx.x * 256 + threadIdx.x;
    const int stride = gridDim.x * 256;
    i32x4* head4 = (i32x4*)(wsi + WS_HEAD);
    i32x4* bmp4  = (i32x4*)(wsi + WS_BMP);
    const i32x4 mone = {-1, -1, -1, -1};
    const i32x4 zero = {0, 0, 0, 0};
    for (int i = tid; i < TOT / 4; i += stride) __builtin_nontemporal_store(mone, head4 + i);
    for (int i = tid; i < TOT / 32 / 4; i += stride) __builtin_nontemporal_store(zero, bmp4 + i);
    if (tid < 1024) ((i32x4*)(wsi + WS_PZ))[tid] = zero;   // PZ+PM (4096 ints)
    if (tid == 0) wsi[WS_CNT] = 0;
    if (blockIdx.x == 0 && threadIdx.x < C_) {
        const int c = threadIdx.x;
        float s1 = g1[c] / sqrtf(v1[c] + EPS_);
        for (int f = 0; f < 10; ++f) wsf[WS_W1T + c * 10 + f] = W1[f * C_ + c] * s1;
        wsf[WS_B1 + c] = b1[c] - m1[c] * s1;
        float s2 = g2[c] / sqrtf(v2[c] + EPS_);
        for (int k = 0; k < C_; ++k) wsf[WS_W2T + c * C_ + k] = W2[k * C_ + c] * s2;
        wsf[WS_B2 + c] = b2[c] - m2[c] * s2;
    }
}

__device__ __forceinline__ int cell_of(float x, float y) {
    int px = (int)floorf((x - PC0) / VS0);
    int py = (int)floorf((y - PC1) / VS1);
    px = px < 0 ? 0 : (px > NX_ - 1 ? NX_ - 1 : px);
    py = py < 0 ? 0 : (py > NY_ - 1 ? NY_ - 1 : py);
    return py * NX_ + px;
}

// Kernel 2: one coalesced sweep — z-mean partials + linked-list insert +
// occupied-list append + bitmap set (first insert per cell).
__global__ __launch_bounds__(256) void pass1(const float* __restrict__ pts,
                                             const int* __restrict__ mask,
                                             float* __restrict__ wsf, int* __restrict__ wsi) {
    const int b = blockIdx.y, t = threadIdx.x;
    const int n = blockIdx.x * 256 + t;
    float sz = 0.f, sm = 0.f;
    if (n < N_ && mask[b * N_ + n]) {
        const size_t pb = ((size_t)b * N_ + n) * 5;
        const float x = pts[pb], y = pts[pb + 1], z = pts[pb + 2];
        const int idx = b * CELLS + cell_of(x, y);
        const int old = atomicExch(&wsi[WS_HEAD + idx], n);
        wsi[WS_NEXT + b * N_ + n] = old;
        if (old == -1) {
            const int li = atomicAdd(&wsi[WS_CNT], 1);
            wsi[WS_LIST + li] = idx;
            atomicOr(&wsi[WS_BMP + (idx >> 5)], 1 << (idx & 31));
        }
        sz = z; sm = 1.f;
    }
    __shared__ float lz[256], lm[256];
    lz[t] = sz; lm[t] = sm;
    __syncthreads();
    for (int s = 128; s > 0; s >>= 1) {
        if (t < s) { lz[t] += lz[t + s]; lm[t] += lm[t + s]; }
        __syncthreads();
    }
    if (t == 0) { wsf[WS_PZ + b * 1024 + blockIdx.x] = lz[0]; wsf[WS_PM + b * 1024 + blockIdx.x] = lm[0]; }
}

// Kernel 3: round-16 body (2-deep pipelined walk, compute-then-zero, no
// overlap — r13/r17 showed any zero/compute concurrency costs +10-12us).
// ONLY change: the chain walk is SCALARIZED via readfirstlane — all 64 lanes
// walk the same chain, so ids/addresses are wave-uniform; proving that to the
// compiler moves NEXT/pts loads onto the scalar pipe (s_load, lgkmcnt),
// removing vector-load issue + VALU addr-gen from the hot loop. Arithmetic
// and visit order unchanged -> bit-identical output.
__global__ __launch_bounds__(256) void fat(const float* __restrict__ pts,
                                           const float* __restrict__ wsf,
                                           const int* __restrict__ wsi,
                                           float* __restrict__ out) {
    __shared__ float red[16];
    const int t    = threadIdx.x;
    const int wid  = t >> 6;
    const int lane = t & 63;
    const int c    = lane;

    // ---- zmean finish: reduce 1024 partials per batch, redundantly per block ----
    float sz0 = 0.f, sm0 = 0.f, sz1 = 0.f, sm1 = 0.f;
#pragma unroll
    for (int k = 0; k < 4; ++k) {
        const int i = t + k * 256;
        sz0 += wsf[WS_PZ + i];        sm0 += wsf[WS_PM + i];
        sz1 += wsf[WS_PZ + 1024 + i]; sm1 += wsf[WS_PM + 1024 + i];
    }
#pragma unroll
    for (int m = 32; m >= 1; m >>= 1) {
        sz0 += __shfl_xor(sz0, m, 64); sm0 += __shfl_xor(sm0, m, 64);
        sz1 += __shfl_xor(sz1, m, 64); sm1 += __shfl_xor(sm1, m, 64);
    }
    if (lane == 0) {
        red[wid * 4 + 0] = sz0; red[wid * 4 + 1] = sm0;
        red[wid * 4 + 2] = sz1; red[wid * 4 + 3] = sm1;
    }
    __syncthreads();
    const float zm0 = (red[0] + red[4] + red[8] + red[12]) /
                      fmaxf(red[1] + red[5] + red[9] + red[13], 1.f);
    const float zm1 = (red[2] + red[6] + red[10] + red[14]) /
                      fmaxf(red[3] + red[7] + red[11] + red[15], 1.f);

    // ---- per-lane folded weights ----
    float w1c[10];
#pragma unroll
    for (int f = 0; f < 10; ++f) w1c[f] = wsf[WS_W1T + c * 10 + f];
    const float b1c = wsf[WS_B1 + c];
    float w2c[C_];
#pragma unroll
    for (int k = 0; k < C_; ++k) w2c[k] = wsf[WS_W2T + c * C_ + k];
    const float b2c = wsf[WS_B2 + c];

    const int W  = blockIdx.x * 4 + wid;
    const int NW = GRID * 4;

    // ---- compute role: occupied cells, scalarized 2-deep pipelined walk ----
    {
        const int cnt = __builtin_amdgcn_readfirstlane(wsi[WS_CNT]);
        for (int e = W; e < cnt; e += NW) {
            const int idx  = __builtin_amdgcn_readfirstlane(wsi[WS_LIST + e]);
            const int b    = idx >> 20;
            const int cell = idx & (CELLS - 1);
            const float pxf = (float)(cell & (NX_ - 1));
            const float pyf = (float)(cell >> 10);
            const float zmean = b ? zm1 : zm0;
            const int nb = b * N_;
            float hmax = 0.f;

            // pipeline state: n0 = current (data in x0..r0), n1 = next id
            int n0 = __builtin_amdgcn_readfirstlane(wsi[WS_HEAD + idx]);
            int n1 = -1;
            float x0 = 0.f, y0 = 0.f, z0 = 0.f, i0 = 0.f, r0 = 0.f;
            float x1 = 0.f, y1 = 0.f, z1 = 0.f, i1 = 0.f, r1 = 0.f;
            if (n0 != -1) {
                const size_t pb = ((size_t)nb + n0) * 5;
                x0 = pts[pb]; y0 = pts[pb + 1]; z0 = pts[pb + 2];
                i0 = pts[pb + 3]; r0 = pts[pb + 4];
                n1 = __builtin_amdgcn_readfirstlane(wsi[WS_NEXT + nb + n0]);
            }
            while (n0 != -1) {
                int n2 = -1;
                if (n1 != -1) {                      // issue next point's loads NOW
                    n2 = __builtin_amdgcn_readfirstlane(wsi[WS_NEXT + nb + n1]);
                    const size_t pb = ((size_t)nb + n1) * 5;
                    x1 = pts[pb]; y1 = pts[pb + 1]; z1 = pts[pb + 2];
                    i1 = pts[pb + 3]; r1 = pts[pb + 4];
                }
                // visit point n0 (data already in registers)
                float a = b1c;
                a = fmaf(x0, w1c[0], a);
                a = fmaf(y0, w1c[1], a);
                a = fmaf(z0, w1c[2], a);
                a = fmaf(i0, w1c[3], a);
                a = fmaf(r0, w1c[4], a);
                a = fmaf(x0 - (pxf * VS0 + PC0 + VS0 * 0.5f), w1c[5], a);
                a = fmaf(y0 - (pyf * VS1 + PC1 + VS1 * 0.5f), w1c[6], a);
                a = fmaf(z0 - zmean,                          w1c[7], a);
                a = fmaf(x0 - (pxf * VS0 + PC0),              w1c[8], a);
                a = fmaf(y0 - (pyf * VS1 + PC1),              w1c[9], a);
                const int h1i = __float_as_int(fmaxf(a, 0.f));   // lane k holds h1[k]
                float ac0 = 0.f, ac1 = 0.f, ac2 = 0.f, ac3 = 0.f;
#pragma unroll
                for (int k = 0; k < 16; ++k) {   // same k-order + 4-way split as rounds 2-17
                    ac0 = fmaf(__int_as_float(__builtin_amdgcn_readlane(h1i, 4 * k + 0)), w2c[4 * k + 0], ac0);
                    ac1 = fmaf(__int_as_float(__builtin_amdgcn_readlane(h1i, 4 * k + 1)), w2c[4 * k + 1], ac1);
                    ac2 = fmaf(__int_as_float(__builtin_amdgcn_readlane(h1i, 4 * k + 2)), w2c[4 * k + 2], ac2);
                    ac3 = fmaf(__int_as_float(__builtin_amdgcn_readlane(h1i, 4 * k + 3)), w2c[4 * k + 3], ac3);
                }
                hmax = fmaxf(hmax, b2c + ((ac0 + ac1) + (ac2 + ac3)));
                // shift pipeline
                n0 = n1; n1 = n2;
                x0 = x1; y0 = y1; z0 = z1; i0 = i1; r0 = r1;
            }
            out[(((size_t)b * C_ + c) << 20) + cell] = hmax;
        }
    }

    // ---- zero role: 2048-cell stripes, one bitmap word per lane ----
    {
        f32x4* out4 = (f32x4*)out;
        const f32x4 z4 = {0.f, 0.f, 0.f, 0.f};
        for (int s = W; s < NSTRIPE; s += NW) {
            const int p  = s >> 9;          // plane = b*64 + ch
            const int q  = s & 511;         // stripe within plane (2048 cells)
            const int bb = p >> 6;
            const int Wd = wsi[WS_BMP + bb * (CELLS / 32) + q * 64 + lane];
            const int ib = (p << 18) + (q << 9);   // f32x4 base index of stripe
            if (__ballot(Wd != 0) == 0ULL) {
#pragma unroll
                for (int k = 0; k < 8; ++k)
                    __builtin_nontemporal_store(z4, out4 + (ib + k * 64 + lane));
            } else {
#pragma unroll
                for (int k = 0; k < 8; ++k) {
                    const unsigned w   = (unsigned)__shfl(Wd, k * 8 + (lane >> 3), 64);
                    const unsigned nib = (w >> ((lane & 7) * 4)) & 0xFu;
                    const int i = ib + k * 64 + lane;
                    if (nib == 0u) {
                        __builtin_nontemporal_store(z4, out4 + i);
                    } else {
#pragma unroll
                        for (int jj = 0; jj < 4; ++jj)
                            if (!((nib >> jj) & 1u)) out[(size_t)i * 4 + jj] = 0.f;
                    }
                }
            }
        }
    }
}

// ---------------- fallback path (round-2, atomic scatter) ----------------
__global__ void prep_weights_fb(const float* __restrict__ W1, const float* __restrict__ g1,
                                const float* __restrict__ b1, const float* __restrict__ m1,
                                const float* __restrict__ v1, const float* __restrict__ W2,
                                const float* __restrict__ g2, const float* __restrict__ b2,
                                const float* __restrict__ m2, const float* __restrict__ v2,
                                float* __restrict__ ws) {
    int c = threadIdx.x;
    if (c >= C_) return;
    float s1 = g1[c] / sqrtf(v1[c] + EPS_);
    for (int f = 0; f < 10; ++f) ws[WS_W1T + c * 10 + f] = W1[f * C_ + c] * s1;
    ws[WS_B1 + c] = b1[c] - m1[c] * s1;
    float s2 = g2[c] / sqrtf(v2[c] + EPS_);
    for (int k = 0; k < C_; ++k) ws[WS_W2T + c * C_ + k] = W2[k * C_ + c] * s2;
    ws[WS_B2 + c] = b2[c] - m2[c] * s2;
}

__global__ void zmean_fb1(const float* __restrict__ pts, const int* __restrict__ mask,
                          float* __restrict__ ws) {
    const int b = blockIdx.y, t = threadIdx.x;
    const int n = blockIdx.x * 256 + t;
    float sz = 0.f, sm = 0.f;
    if (n < N_ && mask[b * N_ + n]) {
        sz = pts[((size_t)b * N_ + n) * 5 + 2];
        sm = 1.f;
    }
    __shared__ float lz[256], lm[256];
    lz[t] = sz; lm[t] = sm;
    __syncthreads();
    for (int s = 128; s > 0; s >>= 1) {
        if (t < s) { lz[t] += lz[t + s]; lm[t] += lm[t + s]; }
        __syncthreads();
    }
    if (t == 0) { ws[WS_PZ + b * 1024 + blockIdx.x] = lz[0]; ws[WS_PM + b * 1024 + blockIdx.x] = lm[0]; }
}

__global__ void zmean_fb2(float* __restrict__ ws) {
    const int b = blockIdx.x, t = threadIdx.x;
    __shared__ float lz[256], lm[256];
    float sz = 0.f, sm = 0.f;
    for (int k = t; k < 1024; k += 256) {
        sz += (k < PBLK) ? ws[WS_PZ + b * 1024 + k] : 0.f;
        sm += (k < PBLK) ? ws[WS_PM + b * 1024 + k] : 0.f;
    }
    lz[t] = sz; lm[t] = sm;
    __syncthreads();
    for (int s = 128; s > 0; s >>= 1) {
        if (t < s) { lz[t] += lz[t + s]; lm[t] += lm[t + s]; }
        __syncthreads();
    }
    if (t == 0) ws[WS_CNT + 2 + b] = lz[0] / fmaxf(lm[0], 1.f);  // stash zmean
}

__global__ __launch_bounds__(256) void pfn_scatter_fb(const float* __restrict__ pts,
                                                      const int* __restrict__ mask,
                                                      const float* __restrict__ ws,
                                                      float* __restrict__ out) {
    const int b = blockIdx.y;
    const int n = blockIdx.x * 256 + threadIdx.x;
    if (n >= N_) return;
    if (!mask[b * N_ + n]) return;
    const float zmean = ws[WS_CNT + 2 + b];
    const size_t pbase = ((size_t)b * N_ + n) * 5;
    const float x = pts[pbase], y = pts[pbase + 1], z = pts[pbase + 2];
    const float it = pts[pbase + 3], rg = pts[pbase + 4];
    const int cell = cell_of(x, y);
    const float pxf = (float)(cell & (NX_ - 1)), pyf = (float)(cell >> 10);
    float aug[10];
    aug[0] = x; aug[1] = y; aug[2] = z; aug[3] = it; aug[4] = rg;
    aug[5] = x - (pxf * VS0 + PC0 + VS0 * 0.5f);
    aug[6] = y - (pyf * VS1 + PC1 + VS1 * 0.5f);
    aug[7] = z - zmean;
    aug[8] = x - (pxf * VS0 + PC0);
    aug[9] = y - (pyf * VS1 + PC1);
    float h1[C_];
#pragma unroll
    for (int c = 0; c < C_; ++c) {
        float acc = ws[WS_B1 + c];
#pragma unroll
        for (int f = 0; f < 10; ++f) acc = fmaf(aug[f], ws[WS_W1T + c * 10 + f], acc);
        h1[c] = fmaxf(acc, 0.f);
    }
    unsigned int* ob = (unsigned int*)out + (size_t)b * C_ * CELLS + cell;
#pragma unroll 4
    for (int c = 0; c < C_; ++c) {
        float acc = ws[WS_B2 + c];
#pragma unroll
        for (int k = 0; k < C_; ++k) acc = fmaf(h1[k], ws[WS_W2T + c * C_ + k], acc);
        if (acc > 0.f) atomicMax(ob + (size_t)c * CELLS, __float_as_uint(acc));
    }
}

extern "C" void kernel_launch(void* const* d_in, const int* in_sizes, int n_in,
                              void* d_out, int out_size, void* d_ws, size_t ws_size,
                              hipStream_t stream) {
    const float* pts  = (const float*)d_in[0];
    const int*   mask = (const int*)d_in[1];
    const float* W1 = (const float*)d_in[2];
    const float* g1 = (const float*)d_in[3];
    const float* b1 = (const float*)d_in[4];
    const float* m1 = (const float*)d_in[5];
    const float* v1 = (const float*)d_in[6];
    const float* W2 = (const float*)d_in[7];
    const float* g2 = (const float*)d_in[8];
    const float* b2 = (const float*)d_in[9];
    const float* m2 = (const float*)d_in[10];
    const float* v2 = (const float*)d_in[11];
    float* wsf = (float*)d_ws;
    int*   wsi = (int*)d_ws;
    float* out = (float*)d_out;

    if (ws_size >= NEED_BYTES) {
        init_prep<<<512, 256, 0, stream>>>(W1, g1, b1, m1, v1, W2, g2, b2, m2, v2, wsf, wsi);
        pass1<<<dim3(PBLK, B_), 256, 0, stream>>>(pts, mask, wsf, wsi);
        fat<<<GRID, 256, 0, stream>>>(pts, wsf, wsi, out);
    } else {
        hipMemsetAsync(d_out, 0, (size_t)out_size * sizeof(float), stream);
        hipMemsetAsync((char*)d_ws + (size_t)WS_PZ * 4, 0, 4096 * 4, stream);
        prep_weights_fb<<<1, 256, 0, stream>>>(W1, g1, b1, m1, v1, W2, g2, b2, m2, v2, wsf);
        zmean_fb1<<<dim3(PBLK, B_), 256, 0, stream>>>(pts, mask, wsf);
        zmean_fb2<<<B_, 256, 0, stream>>>(wsf);
        pfn_scatter_fb<<<dim3((N_ + 255) / 256, B_), 256, 0, stream>>>(pts, mask, wsf, out);
    }
}